// Round 8
// baseline (193.845 us; speedup 1.0000x reference)
//
#include <hip/hip_runtime.h>
#include <cstdint>
#include <cstddef>
#include <math.h>

typedef uint16_t bf16;  // raw bf16 bits
typedef __attribute__((ext_vector_type(8))) __bf16 bf16x8;
typedef __attribute__((ext_vector_type(2))) float f32x2;
typedef __attribute__((ext_vector_type(4))) float f32x4;
typedef __attribute__((ext_vector_type(16))) float f32x16;

#define MFMA16(a,b,c) __builtin_amdgcn_mfma_f32_16x16x32_bf16((a),(b),(c),0,0,0)
#define MFMA32(a,b,c) __builtin_amdgcn_mfma_f32_32x32x16_bf16((a),(b),(c),0,0,0)

__device__ __forceinline__ uint16_t f2bf(float f){
  uint32_t u = __float_as_uint(f);
  return (uint16_t)((u + 0x7fffu + ((u >> 16) & 1u)) >> 16);
}
__device__ __forceinline__ uint32_t pk2(float lo, float hi){
  return (uint32_t)f2bf(lo) | ((uint32_t)f2bf(hi) << 16);
}

__device__ __forceinline__ void gload_lds16(const void* g, void* l){
  __builtin_amdgcn_global_load_lds((const __attribute__((address_space(1))) void*)g,
                                   (__attribute__((address_space(3))) void*)l, 16, 0, 0);
}

// ---------------- elementwise fp32 -> bf16 ----------------
__global__ void k_convert(const float* __restrict__ in, bf16* __restrict__ out, int n){
  int i = (blockIdx.x * 256 + threadIdx.x) * 4;
  if (i >= n) return;
  float4 v = *reinterpret_cast<const float4*>(in + i);
  uint32_t lo = pk2(v.x, v.y);
  uint32_t hi = pk2(v.z, v.w);
  uint2 pkv = make_uint2(lo, hi);
  *reinterpret_cast<uint2*>(out + i) = pkv;
}

// ---------------- W [R][C] f32 -> Wt [C][R] bf16, 64x64 tile, vectorized ----------------
__global__ void k_transposeW(const float* __restrict__ in, bf16* __restrict__ out, int R, int C){
  __shared__ float tile[64][65];
  int c0 = blockIdx.x * 64, r0 = blockIdx.y * 64;
  int t = threadIdx.x;
  int fx = t & 15, fy = t >> 4;
  #pragma unroll
  for (int i = 0; i < 4; i++){
    int r = fy + i*16;
    float4 v = *reinterpret_cast<const float4*>(in + (size_t)(r0 + r)*C + c0 + fx*4);
    tile[r][fx*4+0] = v.x; tile[r][fx*4+1] = v.y;
    tile[r][fx*4+2] = v.z; tile[r][fx*4+3] = v.w;
  }
  __syncthreads();
  int gx = t & 7, gy = t >> 3;
  #pragma unroll
  for (int i = 0; i < 2; i++){
    int c = gy + i*32;
    int rr = gx*8;
    union { bf16 h[8]; uint4 u; } pk_;
    #pragma unroll
    for (int j = 0; j < 8; j++) pk_.h[j] = f2bf(tile[rr+j][c]);
    *reinterpret_cast<uint4*>(out + (size_t)(c0 + c)*R + r0 + rr) = pk_.u;
  }
}

// ---------------- 128x128 bf16 GEMM core (A row-major, Bt row-major [N][K]) ----------------
__device__ __forceinline__ void gemm128_core(
    const bf16* __restrict__ Abase, const bf16* __restrict__ Btbase,
    int lda, int ldb, int K, bf16* As, bf16* Bs, f32x4 acc[4][4])
{
  const int tid = threadIdx.x;
  const int wid = tid >> 6, lane = tid & 63;
  const int wr = wid >> 1, wc = wid & 1;
  const int lr = lane & 15, lg = lane >> 4;
  const f32x4 vzero = {0.f, 0.f, 0.f, 0.f};

  #pragma unroll
  for (int m = 0; m < 4; m++)
    #pragma unroll
    for (int n = 0; n < 4; n++)
      acc[m][n] = vzero;

  int srcA[4], srcB[4], dOff[4];
  #pragma unroll
  for (int i = 0; i < 4; i++){
    int d = i*4096 + wid*1024 + lane*16;
    int row = d >> 7, sp = (d >> 4) & 7;
    int sl = sp ^ (row & 7);
    srcA[i] = row * lda + sl * 8;
    srcB[i] = row * ldb + sl * 8;
    dOff[i] = i*4096 + wid*1024;
  }

  for (int k0 = 0; k0 < K; k0 += 64){
    #pragma unroll
    for (int i = 0; i < 4; i++)
      gload_lds16(Abase + k0 + srcA[i], (char*)As + dOff[i]);
    #pragma unroll
    for (int i = 0; i < 4; i++)
      gload_lds16(Btbase + k0 + srcB[i], (char*)Bs + dOff[i]);
    __syncthreads();
    #pragma unroll
    for (int ks = 0; ks < 2; ks++){
      bf16x8 af[4], bfr[4];
      #pragma unroll
      for (int m = 0; m < 4; m++){
        int row = wr*64 + m*16 + lr;
        int sp = (ks*4 + lg) ^ (row & 7);
        af[m] = *reinterpret_cast<const bf16x8*>(As + row*64 + sp*8);
      }
      #pragma unroll
      for (int n = 0; n < 4; n++){
        int row = wc*64 + n*16 + lr;
        int sp = (ks*4 + lg) ^ (row & 7);
        bfr[n] = *reinterpret_cast<const bf16x8*>(Bs + row*64 + sp*8);
      }
      #pragma unroll
      for (int m = 0; m < 4; m++)
        #pragma unroll
        for (int n = 0; n < 4; n++)
          acc[m][n] = MFMA16(af[m], bfr[n], acc[m][n]);
    }
    __syncthreads();
  }
}

// ---------------- fused QKV projection (V written pre-transposed) ----------------
__global__ __launch_bounds__(256, 2) void k_qkv(
    const bf16* __restrict__ xb,
    const bf16* __restrict__ WqT, const bf16* __restrict__ WkT, const bf16* __restrict__ WvT,
    const float* __restrict__ bq, const float* __restrict__ bk, const float* __restrict__ bv,
    bf16* __restrict__ qo, bf16* __restrict__ ko, bf16* __restrict__ vtp)
{
  __shared__ __align__(16) bf16 As[128*64];
  __shared__ __align__(16) bf16 Bs[128*64];
  int by = blockIdx.y;
  const bf16* Bt; const float* bias; int mode; int y = 0; float scale = 1.f;
  if (by < 16){      Bt = WqT + (size_t)by*128*2048;      bias = bq + by*128; mode = 0; y = by;   scale = 0.18033688011112042f; } // 0.125*log2(e)
  else if (by < 20){ y = by-16; Bt = WkT + (size_t)y*128*2048; bias = bk + y*128; mode = 1; }
  else {             y = by-20; Bt = WvT + (size_t)y*128*2048; bias = bv + y*128; mode = 2; }
  int m0 = blockIdx.x * 128;
  f32x4 acc[4][4];
  gemm128_core(xb + (size_t)m0*2048, Bt, 2048, 2048, 2048, As, Bs, acc);
  const int tid = threadIdx.x, wid = tid >> 6, lane = tid & 63;
  const int wr = wid >> 1, wc = wid & 1, lr = lane & 15, lg = lane >> 4;
  if (mode == 2){
    // V^T: vtp[b][col][t]
    #pragma unroll
    for (int n = 0; n < 4; n++){
      int cl = wc*64 + n*16 + lr;
      float bb = bias[cl];
      #pragma unroll
      for (int m = 0; m < 4; m++){
        int row0 = m0 + wr*64 + m*16 + lg*4;
        int bi = row0 >> 11, tl = row0 & 2047;
        union { bf16 h[4]; uint2 u; } pk_;
        #pragma unroll
        for (int r = 0; r < 4; r++) pk_.h[r] = f2bf(acc[m][n][r] + bb);
        *reinterpret_cast<uint2*>(vtp + ((size_t)bi*512 + y*128 + cl)*2048 + tl) = pk_.u;
      }
    }
  } else {
    bf16* outp = (mode == 0) ? (qo + y*128) : (ko + y*128);
    int ldc = (mode == 0) ? 2048 : 512;
    #pragma unroll
    for (int n = 0; n < 4; n++){
      int col = wc*64 + n*16 + lr;
      float bb = bias[col];
      #pragma unroll
      for (int m = 0; m < 4; m++)
        #pragma unroll
        for (int r = 0; r < 4; r++){
          int row = m0 + wr*64 + m*16 + lg*4 + r;
          outp[(size_t)row*ldc + col] = f2bf((acc[m][n][r] + bb) * scale);
        }
    }
  }
}

// ---------------- O projection (fp32 out) ----------------
__global__ __launch_bounds__(256, 2) void k_oproj(
    const bf16* __restrict__ ab, const bf16* __restrict__ WoT,
    const float* __restrict__ bo, float* __restrict__ outp)
{
  __shared__ __align__(16) bf16 As[128*64];
  __shared__ __align__(16) bf16 Bs[128*64];
  int m0 = blockIdx.x * 128, n0 = blockIdx.y * 128;
  f32x4 acc[4][4];
  gemm128_core(ab + (size_t)m0*2048, WoT + (size_t)n0*2048, 2048, 2048, 2048, As, Bs, acc);
  const int tid = threadIdx.x, wid = tid >> 6, lane = tid & 63;
  const int wr = wid >> 1, wc = wid & 1, lr = lane & 15, lg = lane >> 4;
  #pragma unroll
  for (int n = 0; n < 4; n++){
    int col = n0 + wc*64 + n*16 + lr;
    float bb = bo[col];
    #pragma unroll
    for (int m = 0; m < 4; m++)
      #pragma unroll
      for (int r = 0; r < 4; r++){
        int row = m0 + wr*64 + m*16 + lg*4 + r;
        outp[(size_t)row*2048 + col] = acc[m][n][r] + bb;
      }
  }
}

// ---------------- flash attention v8: counted vmcnt + raw barrier (T3/T4), 3-buffer LDS ----------------
// grid (4 qtiles, 64 bh) = 256 blocks = 1/CU. 8 waves x 64 q-rows (2 groups), QBLK=512, KVBLK=128.
// LDS: K buffers 3x16KB at [0,49152); V^T buffers 3x16KB at [49152,98304).
// Pipeline depth 2: per iter wait vmcnt(4) (tile t landed, t+1 in flight), RAW s_barrier
// (no drain -- loads stay outstanding across it), stage t+2, compute t.
__global__ __launch_bounds__(512, 2) void k_flash(
    const bf16* __restrict__ q, const bf16* __restrict__ kmat,
    const bf16* __restrict__ vt, bf16* __restrict__ ao)
{
  __shared__ __align__(16) char lds[98304];
  const int tid = threadIdx.x;
  const int wid = tid >> 6, lane = tid & 63;
  const int l31 = lane & 31, hi = lane >> 5;
  const int bh = blockIdx.y;
  const int b = bh >> 5, hq = bh & 31, kvh = hq >> 2;
  const int qt = blockIdx.x;
  const int qrow0 = b*2048 + qt*512 + wid*64;

  // Q fragments: qf[g][t][j] = Q[q = g*32 + l31][d = 16t + 8hi + j]
  bf16x8 qf[2][4];
  #pragma unroll
  for (int g = 0; g < 2; g++){
    const bf16* qrow = q + (size_t)(qrow0 + g*32 + l31)*2048 + hq*64 + hi*8;
    #pragma unroll
    for (int t = 0; t < 4; t++)
      qf[g][t] = *reinterpret_cast<const bf16x8*>(qrow + t*16);
  }

  f32x16 oacc[2][2];
  #pragma unroll
  for (int g = 0; g < 2; g++)
    #pragma unroll
    for (int n = 0; n < 2; n++)
      #pragma unroll
      for (int r = 0; r < 16; r++) oacc[g][n][r] = 0.f;
  float rsg[2][2];
  rsg[0][0]=0.f; rsg[0][1]=0.f; rsg[1][0]=0.f; rsg[1][1]=0.f;
  const f32x16 zv = {0.f,0.f,0.f,0.f,0.f,0.f,0.f,0.f,0.f,0.f,0.f,0.f,0.f,0.f,0.f,0.f};

  // precomputed per-lane LDS read addresses within a 16KB buffer
  const int r7 = l31 & 7;
  int A[4];
  #pragma unroll
  for (int j = 0; j < 4; j++)
    A[j] = l31*128 + (((2*j + hi) ^ r7) << 4);

  const bf16* kbase = kmat + (size_t)b*2048*512 + kvh*64;
  const bf16* vbase = vt + ((size_t)b*512 + kvh*64)*2048;

  // staging: K tile 16KB (2 issues), V tile 16KB as 2 s-halves (2 issues); pre-swizzled source
  int kSrc[2], vSrc[2];
  const int dOf = wid*1024;
  #pragma unroll
  for (int i = 0; i < 2; i++){
    int kdb = i*8192 + tid*16;
    int krow = kdb >> 7, ksp = (kdb >> 4) & 7, ksl = ksp ^ (krow & 7);
    kSrc[i] = krow*512 + ksl*8;
    int o = tid*16;
    int vrow = o >> 7, vsp = (o >> 4) & 7, vsl = vsp ^ (vrow & 7);
    vSrc[i] = vrow*2048 + i*64 + vsl*8;
  }

  // bo = buffer byte offset (0 / 16384 / 32768)
  #define STAGE(bo, st_) do { \
    const bf16* kb_ = kbase + (size_t)(st_)*128*512; \
    const bf16* vb_ = vbase + (st_)*128; \
    gload_lds16(kb_ + kSrc[0], lds + (bo) + dOf); \
    gload_lds16(kb_ + kSrc[1], lds + (bo) + 8192 + dOf); \
    gload_lds16(vb_ + vSrc[0], lds + 49152 + (bo) + dOf); \
    gload_lds16(vb_ + vSrc[1], lds + 49152 + (bo) + 8192 + dOf); \
  } while(0)

  #define LDK(j, imm) (*reinterpret_cast<const bf16x8*>(lds + kOff + A[j] + (imm)))
  #define LDV(j, imm) (*reinterpret_cast<const bf16x8*>(lds + 49152 + kOff + A[j] + (imm)))

  STAGE(0, 0);
  STAGE(16384, 1);

  int kOff = 0;        // compute buffer
  int sOff = 32768;    // stage buffer for tile st+2
  for (int st = 0; st < 16; st++){
    // tile st's 4 loads (issued 2 iters ago) retired; tile st+1's 4 may remain in flight.
    if (st == 15) asm volatile("s_waitcnt vmcnt(0)" ::: "memory");
    else          asm volatile("s_waitcnt vmcnt(4)" ::: "memory");
    __builtin_amdgcn_sched_barrier(0);
    __builtin_amdgcn_s_barrier();          // raw barrier: no vmcnt drain
    __builtin_amdgcn_sched_barrier(0);
    if (st < 14){
      STAGE(sOff, st+2);
      sOff = (sOff == 32768) ? 0 : sOff + 16384;
    }

    #pragma unroll
    for (int c = 0; c < 2; c++){
      // S^T = K @ Q^T over k-rows [64c, 64c+64): each af read feeds both q-groups
      f32x16 sc[2][2];
      __builtin_amdgcn_s_setprio(1);
      #pragma unroll
      for (int t = 0; t < 4; t++){
        bf16x8 af0 = LDK(t, c*8192);
        bf16x8 af1 = LDK(t, c*8192 + 4096);
        if (t == 0){
          sc[0][0] = MFMA32(af0, qf[0][0], zv);
          sc[1][0] = MFMA32(af0, qf[1][0], zv);
          sc[0][1] = MFMA32(af1, qf[0][0], zv);
          sc[1][1] = MFMA32(af1, qf[1][0], zv);
        } else {
          sc[0][0] = MFMA32(af0, qf[0][t], sc[0][0]);
          sc[1][0] = MFMA32(af0, qf[1][t], sc[1][0]);
          sc[0][1] = MFMA32(af1, qf[0][t], sc[0][1]);
          sc[1][1] = MFMA32(af1, qf[1][t], sc[1][1]);
        }
      }
      __builtin_amdgcn_s_setprio(0);

      // softmax per group: p = exp2(s), cvt_pk pack, permlane32 half-exchange
      uint32_t pw[2][2][8];
      #pragma unroll
      for (int g = 0; g < 2; g++){
        #pragma unroll
        for (int n = 0; n < 2; n++)
          #pragma unroll
          for (int j = 0; j < 8; j++){
            float plo = __builtin_amdgcn_exp2f(sc[g][n][2*j]);
            float phi = __builtin_amdgcn_exp2f(sc[g][n][2*j+1]);
            rsg[g][j & 1] += plo + phi;
            asm("v_cvt_pk_bf16_f32 %0, %1, %2" : "=v"(pw[g][n][j]) : "v"(plo), "v"(phi));
          }
        #pragma unroll
        for (int n = 0; n < 2; n++)
          #pragma unroll
          for (int h = 0; h < 2; h++){
            asm volatile("v_permlane32_swap_b32 %0, %1" : "+v"(pw[g][n][h*4+0]), "+v"(pw[g][n][h*4+2]));
            asm volatile("v_permlane32_swap_b32 %0, %1" : "+v"(pw[g][n][h*4+1]), "+v"(pw[g][n][h*4+3]));
          }
      }

      // PV: O += P @ V  — each vf read feeds both q-groups
      __builtin_amdgcn_s_setprio(1);
      #pragma unroll
      for (int kk = 0; kk < 4; kk++){
        int n = kk >> 1, h = kk & 1;
        union { uint32_t w[4]; bf16x8 v; } pa0, pa1;
        #pragma unroll
        for (int w_ = 0; w_ < 4; w_++){ pa0.w[w_] = pw[0][n][h*4+w_]; pa1.w[w_] = pw[1][n][h*4+w_]; }
        #pragma unroll
        for (int nd = 0; nd < 2; nd++){
          bf16x8 vf = LDV(kk, c*8192 + nd*4096);
          oacc[0][nd] = MFMA32(pa0.v, vf, oacc[0][nd]);
          oacc[1][nd] = MFMA32(pa1.v, vf, oacc[1][nd]);
        }
      }
      __builtin_amdgcn_s_setprio(0);
    }
    kOff = (kOff == 32768) ? 0 : kOff + 16384;
  }
  #undef STAGE
  #undef LDK
  #undef LDV

  // finalize per group: l[q] = rs(lane q) + rs(lane q+32)
  #pragma unroll
  for (int g = 0; g < 2; g++){
    float rs = rsg[g][0] + rsg[g][1];
    float l = rs + __shfl_xor(rs, 32);
    float linv = 1.f / l;
    float lv[16];
    #pragma unroll
    for (int r = 0; r < 16; r++){
      int qi = (r & 3) + 8*(r >> 2) + 4*hi;
      lv[r] = __shfl(linv, qi);
    }
    #pragma unroll
    for (int nd = 0; nd < 2; nd++)
      #pragma unroll
      for (int r = 0; r < 16; r++){
        int qi = (r & 3) + 8*(r >> 2) + 4*hi;
        int row = qrow0 + g*32 + qi;
        ao[(size_t)row*2048 + hq*64 + nd*32 + l31] = f2bf(oacc[g][nd][r] * lv[r]);
      }
  }
}

// ---------------- host launcher ----------------
extern "C" void kernel_launch(void* const* d_in, const int* in_sizes, int n_in,
                              void* d_out, int out_size, void* d_ws, size_t ws_size,
                              hipStream_t stream)
{
  const float* x  = (const float*)d_in[0];
  const float* Wq = (const float*)d_in[1];
  const float* bq = (const float*)d_in[2];
  const float* Wk = (const float*)d_in[3];
  const float* bk = (const float*)d_in[4];
  const float* Wv = (const float*)d_in[5];
  const float* bv = (const float*)d_in[6];
  const float* Wo = (const float*)d_in[7];
  const float* bo = (const float*)d_in[8];
  float* out = (float*)d_out;

  char* ws = (char*)d_ws;
  size_t off = 0;
  auto alloc = [&](size_t bytes){ char* p = ws + off; off += (bytes + 255) & ~(size_t)255; return p; };
  bf16* xb  = (bf16*)alloc(2*2048*2048*2);   // x bf16 (reused as attnout later)
  bf16* WqT = (bf16*)alloc(2048*2048*2);
  bf16* WkT = (bf16*)alloc(512*2048*2);
  bf16* WvT = (bf16*)alloc(512*2048*2);
  bf16* WoT = (bf16*)alloc(2048*2048*2);
  bf16* qb  = (bf16*)alloc(4096*2048*2);
  bf16* kb  = (bf16*)alloc((size_t)4096*512*2);
  bf16* vtb = (bf16*)alloc((size_t)4096*512*2);
  bf16* aob = xb;  // alias: x_bf16 dead after projections

  k_convert<<<8192, 256, 0, stream>>>(x, xb, 2*2048*2048);
  k_transposeW<<<dim3(32,32), 256, 0, stream>>>(Wq, WqT, 2048, 2048);
  k_transposeW<<<dim3(8,32),  256, 0, stream>>>(Wk, WkT, 2048, 512);
  k_transposeW<<<dim3(8,32),  256, 0, stream>>>(Wv, WvT, 2048, 512);
  k_transposeW<<<dim3(32,32), 256, 0, stream>>>(Wo, WoT, 2048, 2048);
  k_qkv<<<dim3(32,24), 256, 0, stream>>>(xb, WqT, WkT, WvT, bq, bk, bv, qb, kb, vtb);
  k_flash<<<dim3(4,64), 512, 0, stream>>>(qb, kb, vtb, aob);
  k_oproj<<<dim3(32,16), 256, 0, stream>>>(aob, WoT, bo, out);
}